// Round 5
// baseline (172.654 us; speedup 1.0000x reference)
//
#include <hip/hip_runtime.h>

typedef __attribute__((ext_vector_type(8))) short bf16x8;
typedef __attribute__((ext_vector_type(4))) float f32x4;

#define LDK 40   // padded A-tile LDS row stride (80 B)

__device__ __forceinline__ float bf2f(unsigned short u) {
    union { unsigned int i; float f; } v; v.i = ((unsigned int)u) << 16; return v.f;
}
__device__ __forceinline__ unsigned short f2bf(float f) {
    union { float f; unsigned int i; } v; v.f = f;
    unsigned int x = v.i;
    return (unsigned short)((x + 0x7FFFu + ((x >> 16) & 1u)) >> 16);  // RNE
}

__device__ __forceinline__ void gload16(const void* g, void* l) {
    __builtin_amdgcn_global_load_lds(
        (const __attribute__((address_space(1))) unsigned int*)g,
        (__attribute__((address_space(3))) unsigned int*)l, 16, 0, 0);
}

#define ASM_LGKM0 { asm volatile("s_waitcnt lgkmcnt(0)" ::: "memory"); \
                    __builtin_amdgcn_sched_barrier(0); }
#define ASM_BAR   asm volatile("s_barrier" ::: "memory")

// ---------------------------------------------------------------------------
// Bt[n][k] = bf16(B[k][n]);  B = proj_w [K=1024][N=256]
// ---------------------------------------------------------------------------
__global__ __launch_bounds__(256) void transpose_b_kernel(
    const float* __restrict__ B, unsigned short* __restrict__ Bt, int K, int N)
{
    __shared__ float tile[32][33];
    int kb = blockIdx.x % (K / 32);
    int nb = blockIdx.x / (K / 32);
    int k0 = kb * 32, n0 = nb * 32;
    int tx = threadIdx.x & 31, ty = threadIdx.x >> 5;
    #pragma unroll
    for (int i = 0; i < 4; ++i)
        tile[ty + 8 * i][tx] = B[(size_t)(k0 + ty + 8 * i) * N + n0 + tx];
    __syncthreads();
    #pragma unroll
    for (int i = 0; i < 4; ++i)
        Bt[(size_t)(n0 + ty + 8 * i) * K + k0 + tx] = f2bf(tile[tx][ty + 8 * i]);
}

// ---------------------------------------------------------------------------
// enc_bf = bf16(A @ B + bias); logit[row] += sum_c (A@B+bias)[row,c]*attn_w[c]
// 64x64 tile, BK=32, 4 waves (2x2 of 32x32). 2-deep software pipeline:
//   A: global->reg (2 sets) -> cvt -> LDS (2 bufs, padded)
//   B: global_load_lds direct (2 bufs, source-swizzled for 2-way banks)
// Raw s_barrier + counted vmcnt(3): next tile's loads never drained mid-loop.
// ---------------------------------------------------------------------------
__global__ __launch_bounds__(256, 4) void gemm_mfma_kernel(
    const float* __restrict__ A, const unsigned short* __restrict__ Bt,
    const float* __restrict__ bias, const float* __restrict__ attn_w,
    unsigned short* __restrict__ C, float* __restrict__ logit,
    int M, int N, int K)
{
    __shared__ __attribute__((aligned(16))) unsigned short AsA[2][64 * LDK];
    __shared__ __attribute__((aligned(16))) unsigned short AsB[2][64 * 32];

    const int tid = threadIdx.x;
    const int bid = blockIdx.x;
    // XCD-chunked swizzle (grid 1024 = 8*128, bijective)
    const int xcd = bid & 7;
    const int j   = bid >> 3;
    const int bn  = (j & 3) * 64;
    const int bm  = (xcd * 32 + (j >> 2)) * 64;

    const int lane = tid & 63;
    const int wave = tid >> 6;
    const int wr = (wave >> 1) * 32;
    const int wc = (wave & 1) * 32;

    // A staging: thread covers 8 contiguous k of one row
    const int srow = tid >> 2;
    const int sk   = (tid & 3) * 8;
    const float* Aptr = A + (size_t)(bm + srow) * K + sk;

    // B staging via global_load_lds: lane ln -> LDS slot (row=ln>>2, sl=ln&3),
    // fetches global slot sl ^ ((row>>1)&3)  (bank swizzle via source perm)
    const int brow = 16 * wave + (lane >> 2);
    const int bsl  = (lane & 3) ^ ((lane >> 3) & 3);
    const unsigned short* Bptr = Bt + (size_t)(bn + brow) * K + bsl * 8;
    unsigned short* ldsB0 = &AsB[0][wave * 512];
    unsigned short* ldsB1 = &AsB[1][wave * 512];

    float4 areg[2][2];
    f32x4 acc[2][2];
    #pragma unroll
    for (int m = 0; m < 2; ++m)
        #pragma unroll
        for (int n = 0; n < 2; ++n)
            acc[m][n] = (f32x4){0.f, 0.f, 0.f, 0.f};

    const int c15 = lane & 15;
    const int g4  = lane >> 4;                    // k-group 0..3
    const int kg8 = g4 * 8;
    const int slB = (g4 ^ ((c15 >> 1) & 3)) * 8;  // swizzled B read slot

    const int nk = K / 32;   // 32 (even)

    // ---- prologue ----
    gload16(Bptr, ldsB0);                           // B(0)
    areg[0][0] = *(const float4*)(Aptr);            // A(0)
    areg[0][1] = *(const float4*)(Aptr + 4);
    asm volatile("s_waitcnt vmcnt(0)" ::: "memory");
    {
        unsigned short tmp[8];
        const float* afp = (const float*)areg[0];
        #pragma unroll
        for (int i = 0; i < 8; ++i) tmp[i] = f2bf(afp[i]);
        *(bf16x8*)&AsA[0][srow * LDK + sk] = *(bf16x8*)&tmp[0];
    }
    gload16(Bptr + 32, ldsB1);                      // B(1)
    areg[1][0] = *(const float4*)(Aptr + 32);       // A(1)
    areg[1][1] = *(const float4*)(Aptr + 36);
    ASM_LGKM0;
    ASM_BAR;

    // ---- main loop: BODY(T, S) with S = T&1 compile-time ----
#define BODY(T, S)                                                            \
    {                                                                         \
        bf16x8 af0 = *(bf16x8*)&AsA[S][(wr + c15) * LDK + kg8];               \
        bf16x8 af1 = *(bf16x8*)&AsA[S][(wr + 16 + c15) * LDK + kg8];          \
        bf16x8 bf0 = *(bf16x8*)&AsB[S][(wc + c15) * 32 + slB];                \
        bf16x8 bf1 = *(bf16x8*)&AsB[S][(wc + 16 + c15) * 32 + slB];           \
        ASM_LGKM0;                                                            \
        ASM_BAR;  /* all waves done reading buf S */                          \
        if ((T) + 2 < nk) {                                                   \
            gload16(Bptr + ((T) + 2) * 32, (S) ? ldsB1 : ldsB0);              \
            areg[S][0] = *(const float4*)(Aptr + ((T) + 2) * 32);             \
            areg[S][1] = *(const float4*)(Aptr + ((T) + 2) * 32 + 4);         \
        }                                                                     \
        __builtin_amdgcn_s_setprio(1);                                        \
        acc[0][0] = __builtin_amdgcn_mfma_f32_16x16x32_bf16(af0, bf0, acc[0][0], 0, 0, 0); \
        acc[0][1] = __builtin_amdgcn_mfma_f32_16x16x32_bf16(af0, bf1, acc[0][1], 0, 0, 0); \
        acc[1][0] = __builtin_amdgcn_mfma_f32_16x16x32_bf16(af1, bf0, acc[1][0], 0, 0, 0); \
        acc[1][1] = __builtin_amdgcn_mfma_f32_16x16x32_bf16(af1, bf1, acc[1][1], 0, 0, 0); \
        __builtin_amdgcn_s_setprio(0);                                        \
        if ((T) + 1 < nk) {                                                   \
            if ((T) + 2 < nk) { asm volatile("s_waitcnt vmcnt(3)" ::: "memory"); } \
            else              { asm volatile("s_waitcnt vmcnt(0)" ::: "memory"); } \
            unsigned short tmp[8];                                            \
            const float* afp = (const float*)areg[1 - (S)];                   \
            _Pragma("unroll")                                                 \
            for (int i = 0; i < 8; ++i) tmp[i] = f2bf(afp[i]);                \
            *(bf16x8*)&AsA[1 - (S)][srow * LDK + sk] = *(bf16x8*)&tmp[0];     \
            ASM_LGKM0;                                                        \
        }                                                                     \
        ASM_BAR;  /* buf 1-S ready */                                         \
    }

    for (int t = 0; t < nk; t += 2) {
        BODY(t, 0)
        BODY(t + 1, 1)
    }
#undef BODY

    // ---- epilogue: C store + fused logit partials ----
    const int col0 = bn + wc + c15;
    const int row0 = bm + wr + g4 * 4;
    float wsum[2][4] = {};
    #pragma unroll
    for (int n = 0; n < 2; ++n) {
        float bv  = bias[col0 + n * 16];
        float awv = attn_w[col0 + n * 16];
        #pragma unroll
        for (int m = 0; m < 2; ++m) {
            #pragma unroll
            for (int i = 0; i < 4; ++i) {
                float cf = acc[m][n][i] + bv;
                C[(size_t)(row0 + m * 16 + i) * N + col0 + n * 16] = f2bf(cf);
                wsum[m][i] += cf * awv;
            }
        }
    }
    #pragma unroll
    for (int m = 0; m < 2; ++m) {
        #pragma unroll
        for (int i = 0; i < 4; ++i) {
            float v = wsum[m][i];
            v += __shfl_xor(v, 1, 64);
            v += __shfl_xor(v, 2, 64);
            v += __shfl_xor(v, 4, 64);
            v += __shfl_xor(v, 8, 64);
            if (c15 == 0) atomicAdd(&logit[row0 + m * 16 + i], v);
        }
    }
}

// ---------------------------------------------------------------------------
// Span attention: ONE WAVE per query, 16-deep hoisted loads (index-clamped).
// ---------------------------------------------------------------------------
__global__ __launch_bounds__(256) void span_kernel(
    const unsigned short* __restrict__ enc, const float* __restrict__ logit,
    const int* __restrict__ s1, const int* __restrict__ e1,
    const int* __restrict__ s2, const int* __restrict__ e2,
    const int* __restrict__ qb, float* __restrict__ out,
    int Q, int seq, int pd)
{
    int lane = threadIdx.x & 63;
    int q = blockIdx.x * 4 + (threadIdx.x >> 6);
    int r  = (q >= Q) ? 1 : 0;
    int qi = q - r * Q;
    int s = r ? s2[qi] : s1[qi];
    int e = r ? e2[qi] : e1[qi];
    int b = qb[qi];
    int len = e - s + 1;                     // 1..32

    const float* lp = logit + (size_t)b * seq + s;
    float lg = (lane < len) ? lp[lane] : -3.4e38f;
    float m = lg;
    #pragma unroll
    for (int off = 32; off; off >>= 1) m = fmaxf(m, __shfl_xor(m, off, 64));
    float p = (lane < len) ? __expf(lg - m) : 0.0f;
    float sum = p;
    #pragma unroll
    for (int off = 32; off; off >>= 1) sum += __shfl_xor(sum, off, 64);
    float inv = 1.0f / sum;

    const unsigned short* ep = enc + ((size_t)b * seq + s) * pd + lane * 4;
    float ax = 0.f, ay = 0.f, az = 0.f, aw = 0.f;

    for (int t0 = 0; t0 < len; t0 += 16) {       // at most 2 chunks
        ushort4 ev[16];
        #pragma unroll
        for (int u = 0; u < 16; ++u) {
            int tc = t0 + u;
            tc = (tc < len) ? tc : (len - 1);    // clamp: avoid NaN from overread
            ev[u] = *(const ushort4*)(ep + (size_t)tc * pd);
        }
        #pragma unroll
        for (int u = 0; u < 16; ++u) {
            float wt = __shfl(p, t0 + u, 64);    // p==0 beyond len
            ax += wt * bf2f(ev[u].x);
            ay += wt * bf2f(ev[u].y);
            az += wt * bf2f(ev[u].z);
            aw += wt * bf2f(ev[u].w);
        }
    }
    float4 res = {ax * inv, ay * inv, az * inv, aw * inv};
    *((float4*)(out + (size_t)q * pd) + lane) = res;
}

// ---------------------------------------------------------------------------
extern "C" void kernel_launch(void* const* d_in, const int* in_sizes, int n_in,
                              void* d_out, int out_size, void* d_ws, size_t ws_size,
                              hipStream_t stream) {
    const float* enc_in = (const float*)d_in[1];
    const int*   s1     = (const int*)d_in[2];
    const int*   e1     = (const int*)d_in[3];
    const int*   qb     = (const int*)d_in[4];
    const int*   s2     = (const int*)d_in[5];
    const int*   e2     = (const int*)d_in[6];
    const float* proj_w = (const float*)d_in[7];
    const float* proj_b = (const float*)d_in[8];
    const float* attn_w = (const float*)d_in[9];
    float* out = (float*)d_out;

    const int Q   = in_sizes[2];            // 8192
    const int pd  = in_sizes[8];            // 256
    const int hd  = in_sizes[7] / pd;       // 1024
    const int seq = 2048;
    const int M   = in_sizes[1] / hd;       // 16384

    unsigned short* enc_bf = (unsigned short*)d_ws;                       // M*pd bf16 (8 MB)
    float*          logit  = (float*)((char*)d_ws + (size_t)M * pd * 2);  // M fp32 (64 KB)
    unsigned short* Btw    = (unsigned short*)((char*)d_ws +
                               (size_t)M * pd * 2 + (size_t)M * 4);       // pd*hd bf16 (512 KB)

    hipMemsetAsync(logit, 0, (size_t)M * sizeof(float), stream);
    transpose_b_kernel<<<(hd / 32) * (pd / 32), 256, 0, stream>>>(proj_w, Btw, hd, pd);
    gemm_mfma_kernel<<<(M / 64) * (pd / 64), 256, 0, stream>>>(
        enc_in, Btw, proj_b, attn_w, enc_bf, logit, M, pd, hd);
    span_kernel<<<2 * Q / 4, 256, 0, stream>>>(
        enc_bf, logit, s1, e1, s2, e2, qb, out, Q, seq, pd);
}